// Round 6
// baseline (249.562 us; speedup 1.0000x reference)
//
#include <hip/hip_runtime.h>
#include <hip/hip_bf16.h>
#include <cstddef>

#define IN_DIM 128
#define MEM 256
#define KTOT 384
#define NLEAF 65536
#define TAIL_TOP 6
#define NBLK_TAIL 8

typedef float f32x4 __attribute__((ext_vector_type(4)));
typedef short s16x8 __attribute__((ext_vector_type(8)));
typedef unsigned int u32;

__device__ inline unsigned short f2bf(float f){
    unsigned int u = __builtin_bit_cast(unsigned int, f);
    u += 0x7fff + ((u >> 16) & 1);
    return (unsigned short)(u >> 16);
}

__device__ inline void gld_lds16(const void* g, void* l){
    __builtin_amdgcn_global_load_lds((const __attribute__((address_space(1))) u32*)g,
                                     (__attribute__((address_space(3))) u32*)l, 16, 0, 0);
}

__device__ inline float fsigm(float x){
    return __builtin_amdgcn_rcpf(1.f + __expf(-x));
}
__device__ inline float ftanh(float x){
    return 2.f * __builtin_amdgcn_rcpf(1.f + __expf(-2.f * x)) - 1.f;
}

// A-arena element offsets: leaf (l=16) at 0, stride 128; levels 15..0 stride 384.
__host__ __device__ inline size_t offA(int l){
    if (l == 16) return 0;
    return 8388608u + 384u * (65536u - (1u << (l + 1)));
}
#define ARENA_ELEMS 33554048u
#define ARENA_PAD   65536u

// device-scope grid barrier for the 8-block tail kernel (all blocks co-resident)
__device__ inline void grid_barrier(unsigned* ctr, unsigned target){
    __syncthreads();
    if (threadIdx.x == 0){
        __threadfence();   // release: all prior global writes visible device-wide
        __hip_atomic_fetch_add(ctr, 1u, __ATOMIC_RELEASE, __HIP_MEMORY_SCOPE_AGENT);
        while (__hip_atomic_load(ctr, __ATOMIC_ACQUIRE, __HIP_MEMORY_SCOPE_AGENT) < target)
            __builtin_amdgcn_s_sleep(1);
    }
    __syncthreads();
    __threadfence();       // acquire: invalidate L1 so fresh data is read
}

// ---------------- pack W: Wp[row][k], original row order; k<128 = W_ih, else W_hh
__global__ void pack_w_kernel(const float* __restrict__ W_ih, const float* __restrict__ b_ih,
                              const float* __restrict__ W_hh, const float* __restrict__ b_hh,
                              unsigned short* __restrict__ Wp, float* __restrict__ bp,
                              unsigned* __restrict__ ctr){
    int row = blockIdx.x;             // 0..1023
    for (int k = threadIdx.x; k < KTOT; k += blockDim.x){
        float v = (k < IN_DIM) ? W_ih[row * IN_DIM + k] : W_hh[row * MEM + (k - IN_DIM)];
        Wp[row * KTOT + k] = f2bf(v);
    }
    if (threadIdx.x == 0){
        bp[row] = b_ih[row] + b_hh[row];
        if (row == 0) *ctr = 0;       // reset tail grid-barrier each replay
    }
}

// ---------------- pack ALL x rows (f32 -> bf16) into the per-level A arena
__global__ void pack_x_kernel(const float* __restrict__ x, unsigned short* __restrict__ Aarena){
    const int TOTAL_G = 131071 * 16;   // 8-elem groups
    for (int g = blockIdx.x * blockDim.x + threadIdx.x; g < TOTAL_G; g += gridDim.x * blockDim.x){
        int i  = g >> 4;               // global node row 0..131070
        int ko = (g & 15) * 8;
        int l  = 31 - __clz(i + 1);
        int j  = i + 1 - (1 << l);
        size_t dst = offA(l) + (size_t)j * ((l == 16) ? 128 : 384) + ko;
        const f32x4* s = (const f32x4*)(x + (size_t)i * IN_DIM + ko);
        f32x4 v0 = s[0], v1 = s[1];
        s16x8 o;
        #pragma unroll
        for (int e = 0; e < 4; ++e){ o[e] = (short)f2bf(v0[e]); o[4+e] = (short)f2bf(v1[e]); }
        *(s16x8*)(Aarena + dst) = o;
    }
}

// ---------------- fused GEMM + LSTM + child-pair reduction (levels 16..7)
// Block: 128 rows x 32 mem cols. Wave (wm,wc): 64 rows x 16 mem; per-lane all 4 gates.
// Double-buffered LDS, counted vmcnt(8); T2 XOR-swizzle both-sides (source+read).
#define BM 128
#define KC 64

template<int NK>
__global__ __launch_bounds__(256) void gemm_lstm_kernel(
    const unsigned short* __restrict__ A, int n,
    const unsigned short* __restrict__ Wp, const float* __restrict__ bp,
    const float* __restrict__ csum_in, int leaf,
    unsigned short* __restrict__ A_next, float* __restrict__ csum_out)
{
    __shared__ __align__(16) unsigned short As[2][BM * KC];   // 2 x 16 KB
    __shared__ __align__(16) unsigned short Bs[2][BM * KC];   // 2 x 16 KB

    const int tid  = threadIdx.x;
    const int lane = tid & 63;
    const int wid  = tid >> 6;
    const int wm   = wid >> 1;            // row half
    const int wc   = wid & 1;             // mem half
    const int row0 = blockIdx.x * BM;
    const int m0   = blockIdx.y * 32;

    const int srow = lane >> 3;                              // 0..7
    const int scol = ((lane & 7) ^ srow) * 8;                // swizzled source slot

    const int mg = m0 + wc * 16 + (lane & 15);

    // ---- prefetch epilogue operands (hidden under the K-loop)
    const float b0 = bp[0 * 256 + mg];
    const float b1 = bp[1 * 256 + mg];
    const float b2 = bp[2 * 256 + mg];
    const float b3 = bp[3 * 256 + mg];
    float cpre[4][4];
    if (!leaf){
        #pragma unroll
        for (int r = 0; r < 4; ++r){
            const int base = row0 + wm * 64 + r * 16 + (lane >> 4) * 4;
            #pragma unroll
            for (int e = 0; e < 4; ++e)
                cpre[r][e] = csum_in[(size_t)(base + e) * MEM + mg];  // always in-allocation
        }
    } else {
        #pragma unroll
        for (int r = 0; r < 4; ++r)
            #pragma unroll
            for (int e = 0; e < 4; ++e) cpre[r][e] = 0.f;
    }

    f32x4 acc[4][4];
    #pragma unroll
    for (int r = 0; r < 4; ++r)
        #pragma unroll
        for (int q = 0; q < 4; ++q)
            acc[r][q] = (f32x4){0.f, 0.f, 0.f, 0.f};

    auto stage = [&](int d, int kk){
        char* asb = (char*)As[d];
        char* bsb = (char*)Bs[d];
        #pragma unroll
        for (int q = 0; q < 4; ++q){
            int t = wid * 4 + q;
            int r = t * 8 + srow;
            gld_lds16(A + (size_t)(row0 + r) * NK + kk + scol, asb + t * 1024);
        }
        #pragma unroll
        for (int q = 0; q < 4; ++q){
            int t = wid * 4 + q;
            int b = t * 8 + srow;
            int grow = (b >> 5) * 256 + m0 + (b & 31);
            gld_lds16(Wp + (size_t)grow * KTOT + kk + scol, bsb + t * 1024);
        }
    };

    constexpr int nIter = NK / KC;
    stage(0, 0);
    int buf = 0;
    #pragma unroll
    for (int it = 0; it < nIter; ++it){
        if (it + 1 < nIter){
            stage(buf ^ 1, (it + 1) * KC);
            asm volatile("s_waitcnt vmcnt(8)" ::: "memory");   // current tile done; next 8 in flight
        } else {
            asm volatile("s_waitcnt vmcnt(0)" ::: "memory");
        }
        __builtin_amdgcn_s_barrier();
        const unsigned short* Ab = As[buf];
        const unsigned short* Bb = Bs[buf];
        #pragma unroll
        for (int ks = 0; ks < 2; ++ks){
            const int slot = ks * 4 + (lane >> 4);
            const int kb = (slot ^ (lane & 7)) * 8;            // swizzled read slot
            s16x8 a[4], b[4];
            #pragma unroll
            for (int r = 0; r < 4; ++r)
                a[r] = *(const s16x8*)(Ab + (wm * 64 + r * 16 + (lane & 15)) * KC + kb);
            #pragma unroll
            for (int q = 0; q < 4; ++q)
                b[q] = *(const s16x8*)(Bb + (q * 32 + wc * 16 + (lane & 15)) * KC + kb);
            #pragma unroll
            for (int r = 0; r < 4; ++r)
                #pragma unroll
                for (int q = 0; q < 4; ++q)
                    acc[r][q] = __builtin_amdgcn_mfma_f32_16x16x32_bf16(a[r], b[q], acc[r][q], 0, 0, 0);
        }
        __builtin_amdgcn_s_barrier();   // all waves done reading buf before restage
        buf ^= 1;
    }

    // -------- epilogue
    #pragma unroll
    for (int r = 0; r < 4; ++r){
        const int base = row0 + wm * 64 + r * 16 + (lane >> 4) * 4;
        float cn[4], hn[4];
        #pragma unroll
        for (int e = 0; e < 4; ++e){
            float iv = acc[r][0][e] + b0;
            float fv = acc[r][1][e] + b1;
            float gv = acc[r][2][e] + b2;
            float ov = acc[r][3][e] + b3;
            float c  = fsigm(fv) * cpre[r][e] + fsigm(iv) * ftanh(gv);
            cn[e] = c;
            hn[e] = fsigm(ov) * ftanh(c);
        }
        if (base < n){
            int p0 = base >> 1;
            A_next[(size_t)p0 * KTOT + IN_DIM + mg] = f2bf(hn[0] + hn[1]);
            csum_out[(size_t)p0 * MEM + mg] = cn[0] + cn[1];
        }
        if (base + 2 < n){
            int p1 = (base >> 1) + 1;
            A_next[(size_t)p1 * KTOT + IN_DIM + mg] = f2bf(hn[2] + hn[3]);
            csum_out[(size_t)p1 * MEM + mg] = cn[2] + cn[3];
        }
    }
}

// ---------------- tail: levels 6..0 + FC fused, 8 blocks, device grid barrier
// Block b: mem cols [b*32, b*32+32) i.e. 128 gate cols. Waves: wm=row 32-half, wc=mem 16-half.
// A/B fragments read directly from global (L2-resident); rows >= n read arena pad (guarded writes).
__global__ __launch_bounds__(256) void tail_kernel(
    const unsigned short* __restrict__ arena,
    const unsigned short* __restrict__ Wp, const float* __restrict__ bp,
    float* cs_in, float* cs_out,
    float* __restrict__ c_root,
    const float* __restrict__ W_fc, const float* __restrict__ b_fc,
    float* __restrict__ out, unsigned* __restrict__ ctr)
{
    const int tid  = threadIdx.x;
    const int lane = tid & 63;
    const int wid  = tid >> 6;
    const int wm   = wid >> 1;            // row 32-half
    const int wc   = wid & 1;             // mem 16-half
    const int m0   = blockIdx.x * 32;
    const int mg   = m0 + wc * 16 + (lane & 15);

    const float b0 = bp[0 * 256 + mg];
    const float b1 = bp[1 * 256 + mg];
    const float b2 = bp[2 * 256 + mg];
    const float b3 = bp[3 * 256 + mg];

    unsigned gen = 0;
    for (int l = TAIL_TOP; l >= 0; --l){
        const int n = 1 << l;
        const unsigned short* Al = arena + offA(l);

        f32x4 acc[2][4];
        #pragma unroll
        for (int r = 0; r < 2; ++r)
            #pragma unroll
            for (int q = 0; q < 4; ++q)
                acc[r][q] = (f32x4){0.f, 0.f, 0.f, 0.f};

        #pragma unroll
        for (int kc = 0; kc < 12; ++kc){
            const int kk = kc * 32 + (lane >> 4) * 8;
            s16x8 a[2], b[4];
            #pragma unroll
            for (int r = 0; r < 2; ++r)
                a[r] = *(const s16x8*)(Al + (size_t)(wm * 32 + r * 16 + (lane & 15)) * KTOT + kk);
            #pragma unroll
            for (int q = 0; q < 4; ++q)
                b[q] = *(const s16x8*)(Wp + (size_t)(q * 256 + mg) * KTOT + kk);
            #pragma unroll
            for (int r = 0; r < 2; ++r)
                #pragma unroll
                for (int q = 0; q < 4; ++q)
                    acc[r][q] = __builtin_amdgcn_mfma_f32_16x16x32_bf16(a[r], b[q], acc[r][q], 0, 0, 0);
        }

        #pragma unroll
        for (int r = 0; r < 2; ++r){
            const int base = wm * 32 + r * 16 + (lane >> 4) * 4;
            float cn[4], hn[4];
            #pragma unroll
            for (int e = 0; e < 4; ++e){
                float iv = acc[r][0][e] + b0;
                float fv = acc[r][1][e] + b1;
                float gv = acc[r][2][e] + b2;
                float ov = acc[r][3][e] + b3;
                float chc = cs_in[(size_t)(base + e) * MEM + mg];   // in-allocation (rows < 65536)
                float c  = fsigm(fv) * chc + fsigm(iv) * ftanh(gv);
                cn[e] = c;
                hn[e] = fsigm(ov) * ftanh(c);
            }
            if (l == 0){
                if (base == 0) c_root[mg] = cn[0];
            } else {
                unsigned short* A_next = (unsigned short*)arena + offA(l - 1);
                if (base < n){
                    int p0 = base >> 1;
                    A_next[(size_t)p0 * KTOT + IN_DIM + mg] = f2bf(hn[0] + hn[1]);
                    cs_out[(size_t)p0 * MEM + mg] = cn[0] + cn[1];
                }
                if (base + 2 < n){
                    int p1 = (base >> 1) + 1;
                    A_next[(size_t)p1 * KTOT + IN_DIM + mg] = f2bf(hn[2] + hn[3]);
                    cs_out[(size_t)p1 * MEM + mg] = cn[2] + cn[3];
                }
            }
        }
        float* t = cs_in; cs_in = cs_out; cs_out = t;   // lockstep swap
        ++gen;
        grid_barrier(ctr, (unsigned)(NBLK_TAIL * gen));
    }

    // -------- FC on block 0: out[cls] = c_root . W_fc[cls] + b_fc[cls]
    if (blockIdx.x == 0){
        int w = wid;                   // 0..3
        for (int cls = w * 3; cls < w * 3 + 3; ++cls){
            float s = 0.f;
            for (int m = lane; m < 256; m += 64)
                s += c_root[m] * W_fc[cls * 256 + m];
            #pragma unroll
            for (int off = 32; off; off >>= 1)
                s += __shfl_down(s, off, 64);
            if (lane == 0) out[cls] = s + b_fc[cls];
        }
    }
}

extern "C" void kernel_launch(void* const* d_in, const int* in_sizes, int n_in,
                              void* d_out, int out_size, void* d_ws, size_t ws_size,
                              hipStream_t stream)
{
    const float* x    = (const float*)d_in[0];
    const float* W_ih = (const float*)d_in[1];
    const float* b_ih = (const float*)d_in[2];
    const float* W_hh = (const float*)d_in[3];
    const float* b_hh = (const float*)d_in[4];
    const float* W_fc = (const float*)d_in[5];
    const float* b_fc = (const float*)d_in[6];
    float* out = (float*)d_out;

    // workspace layout (bytes)
    const size_t OFF_WP = 0;                                   // 786432
    const size_t OFF_BP = 786432;                              // 4096
    const size_t OFF_A  = 790528;                              // (33554048+65536)*2
    const size_t OFF_CS0 = OFF_A + (size_t)(ARENA_ELEMS + ARENA_PAD) * 2;   // 33554432
    const size_t OFF_CS1 = OFF_CS0 + 33554432;                 // 33554432
    const size_t OFF_CR  = OFF_CS1 + 33554432;                 // 1024
    const size_t OFF_CTR = OFF_CR + 1024;                      // 64
    const size_t NEEDED  = OFF_CTR + 64;
    if (ws_size < NEEDED) return;

    char* ws = (char*)d_ws;
    unsigned short* Wp    = (unsigned short*)(ws + OFF_WP);
    float* bp             = (float*)(ws + OFF_BP);
    unsigned short* arena = (unsigned short*)(ws + OFF_A);
    float* cs0            = (float*)(ws + OFF_CS0);
    float* cs1            = (float*)(ws + OFF_CS1);
    float* c_root         = (float*)(ws + OFF_CR);
    unsigned* ctr         = (unsigned*)(ws + OFF_CTR);

    pack_w_kernel<<<dim3(1024), dim3(128), 0, stream>>>(W_ih, b_ih, W_hh, b_hh, Wp, bp, ctr);
    pack_x_kernel<<<dim3(2048), dim3(256), 0, stream>>>(x, arena);

    // ---- leaf level (l=16): n=65536, K=128; writes hsum into A(15), csum into cs0
    gemm_lstm_kernel<IN_DIM><<<dim3(NLEAF / BM, 8), dim3(256), 0, stream>>>(
        arena + offA(16), NLEAF, Wp, bp,
        nullptr, 1, arena + offA(15), cs0);

    float* cs_in = cs0; float* cs_out = cs1;
    for (int l = 15; l >= 7; --l){
        int n = 1 << l;
        gemm_lstm_kernel<KTOT><<<dim3(n / BM, 8), dim3(256), 0, stream>>>(
            arena + offA(l), n, Wp, bp,
            cs_in, 0, arena + offA(l - 1), cs_out);
        float* t = cs_in; cs_in = cs_out; cs_out = t;
    }

    // ---- tail: levels 6..0 + FC in one kernel (8 co-resident blocks + grid barrier)
    tail_kernel<<<dim3(NBLK_TAIL), dim3(256), 0, stream>>>(
        arena, Wp, bp, cs_in, cs_out, c_root, W_fc, b_fc, out, ctr);
}

// Round 7
// 236.466 us; speedup vs baseline: 1.0554x; 1.0554x over previous
//
#include <hip/hip_runtime.h>
#include <hip/hip_bf16.h>
#include <cstddef>

#define IN_DIM 128
#define MEM 256
#define KTOT 384
#define NLEAF 65536
#define TAIL_TOP 6
#define NBLK_TAIL 8

typedef float f32x4 __attribute__((ext_vector_type(4)));
typedef short s16x8 __attribute__((ext_vector_type(8)));
typedef unsigned int u32;

__device__ inline unsigned short f2bf(float f){
    unsigned int u = __builtin_bit_cast(unsigned int, f);
    u += 0x7fff + ((u >> 16) & 1);
    return (unsigned short)(u >> 16);
}

__device__ inline void gld_lds16(const void* g, void* l){
    __builtin_amdgcn_global_load_lds((const __attribute__((address_space(1))) u32*)g,
                                     (__attribute__((address_space(3))) u32*)l, 16, 0, 0);
}

__device__ inline float fsigm(float x){
    return __builtin_amdgcn_rcpf(1.f + __expf(-x));
}
__device__ inline float ftanh(float x){
    return 2.f * __builtin_amdgcn_rcpf(1.f + __expf(-2.f * x)) - 1.f;
}

// A-arena element offsets: leaf (l=16) at 0, stride 128; levels 15..0 stride 384.
__host__ __device__ inline size_t offA(int l){
    if (l == 16) return 0;
    return 8388608u + 384u * (65536u - (1u << (l + 1)));
}
#define ARENA_ELEMS 33554048u
#define ARENA_PAD   65536u

// device-scope grid barrier for the 8-block tail kernel (all blocks co-resident)
__device__ inline void grid_barrier(unsigned* ctr, unsigned target){
    __syncthreads();
    if (threadIdx.x == 0){
        __threadfence();   // release: all prior global writes visible device-wide
        __hip_atomic_fetch_add(ctr, 1u, __ATOMIC_RELEASE, __HIP_MEMORY_SCOPE_AGENT);
        while (__hip_atomic_load(ctr, __ATOMIC_ACQUIRE, __HIP_MEMORY_SCOPE_AGENT) < target)
            __builtin_amdgcn_s_sleep(1);
    }
    __syncthreads();
    __threadfence();       // acquire: invalidate caches so fresh data is read
}

// ---------------- pack W: Wp[row][k], original row order; k<128 = W_ih, else W_hh
__global__ void pack_w_kernel(const float* __restrict__ W_ih, const float* __restrict__ b_ih,
                              const float* __restrict__ W_hh, const float* __restrict__ b_hh,
                              unsigned short* __restrict__ Wp, float* __restrict__ bp,
                              unsigned* __restrict__ ctr){
    int row = blockIdx.x;             // 0..1023
    for (int k = threadIdx.x; k < KTOT; k += blockDim.x){
        float v = (k < IN_DIM) ? W_ih[row * IN_DIM + k] : W_hh[row * MEM + (k - IN_DIM)];
        Wp[row * KTOT + k] = f2bf(v);
    }
    if (threadIdx.x == 0){
        bp[row] = b_ih[row] + b_hh[row];
        if (row == 0) *ctr = 0;       // reset tail grid-barrier each replay
    }
}

// ---------------- pack ALL x rows (f32 -> bf16) into the per-level A arena
__global__ void pack_x_kernel(const float* __restrict__ x, unsigned short* __restrict__ Aarena){
    const int TOTAL_G = 131071 * 16;   // 8-elem groups
    for (int g = blockIdx.x * blockDim.x + threadIdx.x; g < TOTAL_G; g += gridDim.x * blockDim.x){
        int i  = g >> 4;               // global node row 0..131070
        int ko = (g & 15) * 8;
        int l  = 31 - __clz(i + 1);
        int j  = i + 1 - (1 << l);
        size_t dst = offA(l) + (size_t)j * ((l == 16) ? 128 : 384) + ko;
        const f32x4* s = (const f32x4*)(x + (size_t)i * IN_DIM + ko);
        f32x4 v0 = s[0], v1 = s[1];
        s16x8 o;
        #pragma unroll
        for (int e = 0; e < 4; ++e){ o[e] = (short)f2bf(v0[e]); o[4+e] = (short)f2bf(v1[e]); }
        *(s16x8*)(Aarena + dst) = o;
    }
}

// ---------------- fused GEMM + LSTM + child-pair reduction (levels 16..7)
// Block: 128 rows x 32 mem cols. Wave (wm,wc): 64 rows x 16 mem; per-lane all 4 gates.
// Double-buffered LDS, counted vmcnt(8); T2 XOR-swizzle both-sides (source+read).
#define BM 128
#define KC 64

template<int NK>
__global__ __launch_bounds__(256) void gemm_lstm_kernel(
    const unsigned short* __restrict__ A, int n,
    const unsigned short* __restrict__ Wp, const float* __restrict__ bp,
    const float* __restrict__ csum_in, int leaf,
    unsigned short* __restrict__ A_next, float* __restrict__ csum_out)
{
    __shared__ __align__(16) unsigned short As[2][BM * KC];   // 2 x 16 KB
    __shared__ __align__(16) unsigned short Bs[2][BM * KC];   // 2 x 16 KB

    const int tid  = threadIdx.x;
    const int lane = tid & 63;
    const int wid  = tid >> 6;
    const int wm   = wid >> 1;            // row half
    const int wc   = wid & 1;             // mem half
    const int row0 = blockIdx.x * BM;
    const int m0   = blockIdx.y * 32;

    const int srow = lane >> 3;                              // 0..7
    const int scol = ((lane & 7) ^ srow) * 8;                // swizzled source slot

    const int mg = m0 + wc * 16 + (lane & 15);

    // ---- prefetch epilogue operands (hidden under the K-loop)
    const float b0 = bp[0 * 256 + mg];
    const float b1 = bp[1 * 256 + mg];
    const float b2 = bp[2 * 256 + mg];
    const float b3 = bp[3 * 256 + mg];
    float cpre[4][4];
    if (!leaf){
        #pragma unroll
        for (int r = 0; r < 4; ++r){
            const int base = row0 + wm * 64 + r * 16 + (lane >> 4) * 4;
            #pragma unroll
            for (int e = 0; e < 4; ++e)
                cpre[r][e] = csum_in[(size_t)(base + e) * MEM + mg];  // always in-allocation
        }
    } else {
        #pragma unroll
        for (int r = 0; r < 4; ++r)
            #pragma unroll
            for (int e = 0; e < 4; ++e) cpre[r][e] = 0.f;
    }

    f32x4 acc[4][4];
    #pragma unroll
    for (int r = 0; r < 4; ++r)
        #pragma unroll
        for (int q = 0; q < 4; ++q)
            acc[r][q] = (f32x4){0.f, 0.f, 0.f, 0.f};

    auto stage = [&](int d, int kk){
        char* asb = (char*)As[d];
        char* bsb = (char*)Bs[d];
        #pragma unroll
        for (int q = 0; q < 4; ++q){
            int t = wid * 4 + q;
            int r = t * 8 + srow;
            gld_lds16(A + (size_t)(row0 + r) * NK + kk + scol, asb + t * 1024);
        }
        #pragma unroll
        for (int q = 0; q < 4; ++q){
            int t = wid * 4 + q;
            int b = t * 8 + srow;
            int grow = (b >> 5) * 256 + m0 + (b & 31);
            gld_lds16(Wp + (size_t)grow * KTOT + kk + scol, bsb + t * 1024);
        }
    };

    constexpr int nIter = NK / KC;
    stage(0, 0);
    int buf = 0;
    #pragma unroll
    for (int it = 0; it < nIter; ++it){
        if (it + 1 < nIter){
            stage(buf ^ 1, (it + 1) * KC);
            asm volatile("s_waitcnt vmcnt(8)" ::: "memory");   // current tile done; next 8 in flight
        } else {
            asm volatile("s_waitcnt vmcnt(0)" ::: "memory");
        }
        __builtin_amdgcn_s_barrier();
        const unsigned short* Ab = As[buf];
        const unsigned short* Bb = Bs[buf];
        #pragma unroll
        for (int ks = 0; ks < 2; ++ks){
            const int slot = ks * 4 + (lane >> 4);
            const int kb = (slot ^ (lane & 7)) * 8;            // swizzled read slot
            s16x8 a[4], b[4];
            #pragma unroll
            for (int r = 0; r < 4; ++r)
                a[r] = *(const s16x8*)(Ab + (wm * 64 + r * 16 + (lane & 15)) * KC + kb);
            #pragma unroll
            for (int q = 0; q < 4; ++q)
                b[q] = *(const s16x8*)(Bb + (q * 32 + wc * 16 + (lane & 15)) * KC + kb);
            #pragma unroll
            for (int r = 0; r < 4; ++r)
                #pragma unroll
                for (int q = 0; q < 4; ++q)
                    acc[r][q] = __builtin_amdgcn_mfma_f32_16x16x32_bf16(a[r], b[q], acc[r][q], 0, 0, 0);
        }
        __builtin_amdgcn_s_barrier();   // all waves done reading buf before restage
        buf ^= 1;
    }

    // -------- epilogue
    #pragma unroll
    for (int r = 0; r < 4; ++r){
        const int base = row0 + wm * 64 + r * 16 + (lane >> 4) * 4;
        float cn[4], hn[4];
        #pragma unroll
        for (int e = 0; e < 4; ++e){
            float iv = acc[r][0][e] + b0;
            float fv = acc[r][1][e] + b1;
            float gv = acc[r][2][e] + b2;
            float ov = acc[r][3][e] + b3;
            float c  = fsigm(fv) * cpre[r][e] + fsigm(iv) * ftanh(gv);
            cn[e] = c;
            hn[e] = fsigm(ov) * ftanh(c);
        }
        if (base < n){
            int p0 = base >> 1;
            A_next[(size_t)p0 * KTOT + IN_DIM + mg] = f2bf(hn[0] + hn[1]);
            csum_out[(size_t)p0 * MEM + mg] = cn[0] + cn[1];
        }
        if (base + 2 < n){
            int p1 = (base >> 1) + 1;
            A_next[(size_t)p1 * KTOT + IN_DIM + mg] = f2bf(hn[2] + hn[3]);
            csum_out[(size_t)p1 * MEM + mg] = cn[2] + cn[3];
        }
    }
}

// ---------------- tail: levels 6..0 + FC fused, 8 blocks, device grid barrier
// Block b: mem cols [b*32, b*32+32). Wp slice (128 rows x 384) preloaded ONCE into LDS
// (96 KB, slot-XOR swizzled) -> barrier fences between levels never re-fetch weights.
__global__ __launch_bounds__(256) void tail_kernel(
    const unsigned short* __restrict__ arena,
    const unsigned short* __restrict__ Wp, const float* __restrict__ bp,
    float* cs_in, float* cs_out,
    float* __restrict__ c_root,
    const float* __restrict__ W_fc, const float* __restrict__ b_fc,
    float* __restrict__ out, unsigned* __restrict__ ctr)
{
    __shared__ __align__(16) unsigned short WpL[128 * KTOT];   // 96 KB

    const int tid  = threadIdx.x;
    const int lane = tid & 63;
    const int wid  = tid >> 6;
    const int wm   = wid >> 1;            // row 32-half
    const int wc   = wid & 1;             // mem 16-half
    const int m0   = blockIdx.x * 32;
    const int mg   = m0 + wc * 16 + (lane & 15);

    // ---- preload Wp slice: 6144 16B-slots; physical slot p holds logical slot (p%48)^(row&7)
    // lds row r -> Wp row (r>>5)*256 + m0 + (r&31)
    #pragma unroll
    for (int i = 0; i < 24; ++i){
        int p0 = wid * 1536 + i * 64;          // wave-uniform dest base slot
        int p  = p0 + lane;                    // this lane's physical slot
        int lrow  = p / 48;
        int pslot = p % 48;
        int lslot = pslot ^ (lrow & 7);
        int grow  = (lrow >> 5) * 256 + m0 + (lrow & 31);
        gld_lds16(Wp + (size_t)grow * KTOT + lslot * 8, (char*)WpL + (size_t)p0 * 16);
    }

    const float b0 = bp[0 * 256 + mg];
    const float b1 = bp[1 * 256 + mg];
    const float b2 = bp[2 * 256 + mg];
    const float b3 = bp[3 * 256 + mg];

    asm volatile("s_waitcnt vmcnt(0)" ::: "memory");
    __builtin_amdgcn_s_barrier();

    unsigned gen = 0;
    for (int l = TAIL_TOP; l >= 0; --l){
        const int n = 1 << l;
        const unsigned short* Al = arena + offA(l);

        f32x4 acc[2][4];
        #pragma unroll
        for (int r = 0; r < 2; ++r)
            #pragma unroll
            for (int q = 0; q < 4; ++q)
                acc[r][q] = (f32x4){0.f, 0.f, 0.f, 0.f};

        #pragma unroll
        for (int kc = 0; kc < 12; ++kc){
            const int ls = kc * 4 + (lane >> 4);               // logical 16B slot
            const int kk = ls * 8;
            const int ps = (ls ^ (lane & 7)) * 8;              // swizzled LDS slot
            s16x8 a[2], b[4];
            #pragma unroll
            for (int r = 0; r < 2; ++r)
                a[r] = *(const s16x8*)(Al + (size_t)(wm * 32 + r * 16 + (lane & 15)) * KTOT + kk);
            #pragma unroll
            for (int q = 0; q < 4; ++q)
                b[q] = *(const s16x8*)(WpL + (q * 32 + wc * 16 + (lane & 15)) * KTOT + ps);
            #pragma unroll
            for (int r = 0; r < 2; ++r)
                #pragma unroll
                for (int q = 0; q < 4; ++q)
                    acc[r][q] = __builtin_amdgcn_mfma_f32_16x16x32_bf16(a[r], b[q], acc[r][q], 0, 0, 0);
        }

        #pragma unroll
        for (int r = 0; r < 2; ++r){
            const int base = wm * 32 + r * 16 + (lane >> 4) * 4;
            float cn[4], hn[4];
            #pragma unroll
            for (int e = 0; e < 4; ++e){
                float iv = acc[r][0][e] + b0;
                float fv = acc[r][1][e] + b1;
                float gv = acc[r][2][e] + b2;
                float ov = acc[r][3][e] + b3;
                float chc = cs_in[(size_t)(base + e) * MEM + mg];   // in-allocation
                float c  = fsigm(fv) * chc + fsigm(iv) * ftanh(gv);
                cn[e] = c;
                hn[e] = fsigm(ov) * ftanh(c);
            }
            if (l == 0){
                if (base == 0) c_root[mg] = cn[0];
            } else {
                unsigned short* A_next = (unsigned short*)arena + offA(l - 1);
                if (base < n){
                    int p0 = base >> 1;
                    A_next[(size_t)p0 * KTOT + IN_DIM + mg] = f2bf(hn[0] + hn[1]);
                    cs_out[(size_t)p0 * MEM + mg] = cn[0] + cn[1];
                }
                if (base + 2 < n){
                    int p1 = (base >> 1) + 1;
                    A_next[(size_t)p1 * KTOT + IN_DIM + mg] = f2bf(hn[2] + hn[3]);
                    cs_out[(size_t)p1 * MEM + mg] = cn[2] + cn[3];
                }
            }
        }
        float* t = cs_in; cs_in = cs_out; cs_out = t;   // lockstep swap
        ++gen;
        grid_barrier(ctr, (unsigned)(NBLK_TAIL * gen));
    }

    // -------- FC on block 0: out[cls] = c_root . W_fc[cls] + b_fc[cls]
    if (blockIdx.x == 0){
        int w = wid;                   // 0..3
        for (int cls = w * 3; cls < w * 3 + 3; ++cls){
            float s = 0.f;
            for (int m = lane; m < 256; m += 64)
                s += c_root[m] * W_fc[cls * 256 + m];
            #pragma unroll
            for (int off = 32; off; off >>= 1)
                s += __shfl_down(s, off, 64);
            if (lane == 0) out[cls] = s + b_fc[cls];
        }
    }
}

extern "C" void kernel_launch(void* const* d_in, const int* in_sizes, int n_in,
                              void* d_out, int out_size, void* d_ws, size_t ws_size,
                              hipStream_t stream)
{
    const float* x    = (const float*)d_in[0];
    const float* W_ih = (const float*)d_in[1];
    const float* b_ih = (const float*)d_in[2];
    const float* W_hh = (const float*)d_in[3];
    const float* b_hh = (const float*)d_in[4];
    const float* W_fc = (const float*)d_in[5];
    const float* b_fc = (const float*)d_in[6];
    float* out = (float*)d_out;

    // workspace layout (bytes)
    const size_t OFF_WP = 0;                                   // 786432
    const size_t OFF_BP = 786432;                              // 4096
    const size_t OFF_A  = 790528;                              // (33554048+65536)*2
    const size_t OFF_CS0 = OFF_A + (size_t)(ARENA_ELEMS + ARENA_PAD) * 2;   // 33554432
    const size_t OFF_CS1 = OFF_CS0 + 33554432;                 // 33554432
    const size_t OFF_CR  = OFF_CS1 + 33554432;                 // 1024
    const size_t OFF_CTR = OFF_CR + 1024;                      // 64
    const size_t NEEDED  = OFF_CTR + 64;
    if (ws_size < NEEDED) return;

    char* ws = (char*)d_ws;
    unsigned short* Wp    = (unsigned short*)(ws + OFF_WP);
    float* bp             = (float*)(ws + OFF_BP);
    unsigned short* arena = (unsigned short*)(ws + OFF_A);
    float* cs0            = (float*)(ws + OFF_CS0);
    float* cs1            = (float*)(ws + OFF_CS1);
    float* c_root         = (float*)(ws + OFF_CR);
    unsigned* ctr         = (unsigned*)(ws + OFF_CTR);

    pack_w_kernel<<<dim3(1024), dim3(128), 0, stream>>>(W_ih, b_ih, W_hh, b_hh, Wp, bp, ctr);
    pack_x_kernel<<<dim3(2048), dim3(256), 0, stream>>>(x, arena);

    // ---- leaf level (l=16): n=65536, K=128; writes hsum into A(15), csum into cs0
    gemm_lstm_kernel<IN_DIM><<<dim3(NLEAF / BM, 8), dim3(256), 0, stream>>>(
        arena + offA(16), NLEAF, Wp, bp,
        nullptr, 1, arena + offA(15), cs0);

    float* cs_in = cs0; float* cs_out = cs1;
    for (int l = 15; l >= 7; --l){
        int n = 1 << l;
        gemm_lstm_kernel<KTOT><<<dim3(n / BM, 8), dim3(256), 0, stream>>>(
            arena + offA(l), n, Wp, bp,
            cs_in, 0, arena + offA(l - 1), cs_out);
        float* t = cs_in; cs_in = cs_out; cs_out = t;
    }

    // ---- tail: levels 6..0 + FC in one kernel (8 co-resident blocks + grid barrier)
    tail_kernel<<<dim3(NBLK_TAIL), dim3(256), 0, stream>>>(
        arena, Wp, bp, cs_in, cs_out, c_root, W_fc, b_fc, out, ctr);
}

// Round 8
// 224.052 us; speedup vs baseline: 1.1139x; 1.0554x over previous
//
#include <hip/hip_runtime.h>
#include <hip/hip_bf16.h>
#include <cstddef>

#define IN_DIM 128
#define MEM 256
#define KTOT 384
#define NLEAF 65536
#define TAIL_TOP 6
#define NBLK_TAIL 8

typedef float f32x4 __attribute__((ext_vector_type(4)));
typedef short s16x8 __attribute__((ext_vector_type(8)));
typedef unsigned int u32;

__device__ inline unsigned short f2bf(float f){
    unsigned int u = __builtin_bit_cast(unsigned int, f);
    u += 0x7fff + ((u >> 16) & 1);
    return (unsigned short)(u >> 16);
}

__device__ inline void gld_lds16(const void* g, void* l){
    __builtin_amdgcn_global_load_lds((const __attribute__((address_space(1))) u32*)g,
                                     (__attribute__((address_space(3))) u32*)l, 16, 0, 0);
}

__device__ inline float fsigm(float x){
    return __builtin_amdgcn_rcpf(1.f + __expf(-x));
}
__device__ inline float ftanh(float x){
    return 2.f * __builtin_amdgcn_rcpf(1.f + __expf(-2.f * x)) - 1.f;
}

// A-arena element offsets: leaf (l=16) at 0, stride 128; levels 15..0 stride 384.
__host__ __device__ inline size_t offA(int l){
    if (l == 16) return 0;
    return 8388608u + 384u * (65536u - (1u << (l + 1)));
}
#define ARENA_ELEMS 33554048u
#define ARENA_PAD   65536u

// device-scope grid barrier for the 8-block tail kernel (all blocks co-resident)
__device__ inline void grid_barrier(unsigned* ctr, unsigned target){
    __syncthreads();
    if (threadIdx.x == 0){
        __threadfence();   // release: all prior global writes visible device-wide
        __hip_atomic_fetch_add(ctr, 1u, __ATOMIC_RELEASE, __HIP_MEMORY_SCOPE_AGENT);
        while (__hip_atomic_load(ctr, __ATOMIC_ACQUIRE, __HIP_MEMORY_SCOPE_AGENT) < target)
            __builtin_amdgcn_s_sleep(1);
    }
    __syncthreads();
    __threadfence();       // acquire: invalidate caches so fresh data is read
}

// ---------------- pack W: Wp[row][k], original row order; k<128 = W_ih, else W_hh
__global__ void pack_w_kernel(const float* __restrict__ W_ih, const float* __restrict__ b_ih,
                              const float* __restrict__ W_hh, const float* __restrict__ b_hh,
                              unsigned short* __restrict__ Wp, float* __restrict__ bp,
                              unsigned* __restrict__ ctr){
    int row = blockIdx.x;             // 0..1023
    for (int k = threadIdx.x; k < KTOT; k += blockDim.x){
        float v = (k < IN_DIM) ? W_ih[row * IN_DIM + k] : W_hh[row * MEM + (k - IN_DIM)];
        Wp[row * KTOT + k] = f2bf(v);
    }
    if (threadIdx.x == 0){
        bp[row] = b_ih[row] + b_hh[row];
        if (row == 0) *ctr = 0;       // reset tail grid-barrier each replay
    }
}

// ---------------- pack ALL x rows (f32 -> bf16) into the per-level A arena
__global__ void pack_x_kernel(const float* __restrict__ x, unsigned short* __restrict__ Aarena){
    const int TOTAL_G = 131071 * 16;   // 8-elem groups
    for (int g = blockIdx.x * blockDim.x + threadIdx.x; g < TOTAL_G; g += gridDim.x * blockDim.x){
        int i  = g >> 4;               // global node row 0..131070
        int ko = (g & 15) * 8;
        int l  = 31 - __clz(i + 1);
        int j  = i + 1 - (1 << l);
        size_t dst = offA(l) + (size_t)j * ((l == 16) ? 128 : 384) + ko;
        const f32x4* s = (const f32x4*)(x + (size_t)i * IN_DIM + ko);
        f32x4 v0 = s[0], v1 = s[1];
        s16x8 o;
        #pragma unroll
        for (int e = 0; e < 4; ++e){ o[e] = (short)f2bf(v0[e]); o[4+e] = (short)f2bf(v1[e]); }
        *(s16x8*)(Aarena + dst) = o;
    }
}

// ---------------- fused GEMM + LSTM + child-pair reduction (levels 16..7)
// Block: 128 rows x 32 mem cols. Wave (wm,wc): 64 rows x 16 mem; per-lane all 4 gates.
// Double-buffered LDS, counted vmcnt(8); T2 XOR-swizzle both-sides (source+read).
#define BM 128
#define KC 64

template<int NK>
__global__ __launch_bounds__(256) void gemm_lstm_kernel(
    const unsigned short* __restrict__ A, int n,
    const unsigned short* __restrict__ Wp, const float* __restrict__ bp,
    const float* __restrict__ csum_in, int leaf,
    unsigned short* __restrict__ A_next, float* __restrict__ csum_out)
{
    __shared__ __align__(16) unsigned short As[2][BM * KC];   // 2 x 16 KB
    __shared__ __align__(16) unsigned short Bs[2][BM * KC];   // 2 x 16 KB

    const int tid  = threadIdx.x;
    const int lane = tid & 63;
    const int wid  = tid >> 6;
    const int wm   = wid >> 1;            // row half
    const int wc   = wid & 1;             // mem half
    const int row0 = blockIdx.x * BM;
    const int m0   = blockIdx.y * 32;

    const int srow = lane >> 3;                              // 0..7
    const int scol = ((lane & 7) ^ srow) * 8;                // swizzled source slot

    const int mg = m0 + wc * 16 + (lane & 15);

    // ---- prefetch epilogue operands (hidden under the K-loop)
    const float b0 = bp[0 * 256 + mg];
    const float b1 = bp[1 * 256 + mg];
    const float b2 = bp[2 * 256 + mg];
    const float b3 = bp[3 * 256 + mg];
    float cpre[4][4];
    if (!leaf){
        #pragma unroll
        for (int r = 0; r < 4; ++r){
            const int base = row0 + wm * 64 + r * 16 + (lane >> 4) * 4;
            #pragma unroll
            for (int e = 0; e < 4; ++e)
                cpre[r][e] = csum_in[(size_t)(base + e) * MEM + mg];  // always in-allocation
        }
    } else {
        #pragma unroll
        for (int r = 0; r < 4; ++r)
            #pragma unroll
            for (int e = 0; e < 4; ++e) cpre[r][e] = 0.f;
    }

    f32x4 acc[4][4];
    #pragma unroll
    for (int r = 0; r < 4; ++r)
        #pragma unroll
        for (int q = 0; q < 4; ++q)
            acc[r][q] = (f32x4){0.f, 0.f, 0.f, 0.f};

    auto stage = [&](int d, int kk){
        char* asb = (char*)As[d];
        char* bsb = (char*)Bs[d];
        #pragma unroll
        for (int q = 0; q < 4; ++q){
            int t = wid * 4 + q;
            int r = t * 8 + srow;
            gld_lds16(A + (size_t)(row0 + r) * NK + kk + scol, asb + t * 1024);
        }
        #pragma unroll
        for (int q = 0; q < 4; ++q){
            int t = wid * 4 + q;
            int b = t * 8 + srow;
            int grow = (b >> 5) * 256 + m0 + (b & 31);
            gld_lds16(Wp + (size_t)grow * KTOT + kk + scol, bsb + t * 1024);
        }
    };

    constexpr int nIter = NK / KC;
    stage(0, 0);
    int buf = 0;
    #pragma unroll
    for (int it = 0; it < nIter; ++it){
        if (it + 1 < nIter){
            stage(buf ^ 1, (it + 1) * KC);
            asm volatile("s_waitcnt vmcnt(8)" ::: "memory");   // current tile done; next 8 in flight
        } else {
            asm volatile("s_waitcnt vmcnt(0)" ::: "memory");
        }
        __builtin_amdgcn_s_barrier();
        const unsigned short* Ab = As[buf];
        const unsigned short* Bb = Bs[buf];
        #pragma unroll
        for (int ks = 0; ks < 2; ++ks){
            const int slot = ks * 4 + (lane >> 4);
            const int kb = (slot ^ (lane & 7)) * 8;            // swizzled read slot
            s16x8 a[4], b[4];
            #pragma unroll
            for (int r = 0; r < 4; ++r)
                a[r] = *(const s16x8*)(Ab + (wm * 64 + r * 16 + (lane & 15)) * KC + kb);
            #pragma unroll
            for (int q = 0; q < 4; ++q)
                b[q] = *(const s16x8*)(Bb + (q * 32 + wc * 16 + (lane & 15)) * KC + kb);
            #pragma unroll
            for (int r = 0; r < 4; ++r)
                #pragma unroll
                for (int q = 0; q < 4; ++q)
                    acc[r][q] = __builtin_amdgcn_mfma_f32_16x16x32_bf16(a[r], b[q], acc[r][q], 0, 0, 0);
        }
        __builtin_amdgcn_s_barrier();   // all waves done reading buf before restage
        buf ^= 1;
    }

    // -------- epilogue
    #pragma unroll
    for (int r = 0; r < 4; ++r){
        const int base = row0 + wm * 64 + r * 16 + (lane >> 4) * 4;
        float cn[4], hn[4];
        #pragma unroll
        for (int e = 0; e < 4; ++e){
            float iv = acc[r][0][e] + b0;
            float fv = acc[r][1][e] + b1;
            float gv = acc[r][2][e] + b2;
            float ov = acc[r][3][e] + b3;
            float c  = fsigm(fv) * cpre[r][e] + fsigm(iv) * ftanh(gv);
            cn[e] = c;
            hn[e] = fsigm(ov) * ftanh(c);
        }
        if (base < n){
            int p0 = base >> 1;
            A_next[(size_t)p0 * KTOT + IN_DIM + mg] = f2bf(hn[0] + hn[1]);
            csum_out[(size_t)p0 * MEM + mg] = cn[0] + cn[1];
        }
        if (base + 2 < n){
            int p1 = (base >> 1) + 1;
            A_next[(size_t)p1 * KTOT + IN_DIM + mg] = f2bf(hn[2] + hn[3]);
            csum_out[(size_t)p1 * MEM + mg] = cn[2] + cn[3];
        }
    }
}

// ---------------- tail: levels 6..0 + FC fused, 8 blocks, device grid barrier
// Block b: mem cols [b*32, b*32+32). Wp slice (128x384) in LDS once (96 KB).
// Per level: batched cooperative stage of the whole A panel (<=48 KB) into LDS
// (single latency shot) + concurrent csum prefetch -> MFMA loop touches no global.
__global__ __launch_bounds__(256) void tail_kernel(
    const unsigned short* __restrict__ arena,
    const unsigned short* __restrict__ Wp, const float* __restrict__ bp,
    float* cs_in, float* cs_out,
    float* __restrict__ c_root,
    const float* __restrict__ W_fc, const float* __restrict__ b_fc,
    float* __restrict__ out, unsigned* __restrict__ ctr)
{
    __shared__ __align__(16) unsigned short WpL[128 * KTOT];   // 96 KB
    __shared__ __align__(16) unsigned short AL[64 * KTOT];     // 48 KB

    const int tid  = threadIdx.x;
    const int lane = tid & 63;
    const int wid  = tid >> 6;
    const int wm   = wid >> 1;            // row 32-half
    const int wc   = wid & 1;             // mem 16-half
    const int m0   = blockIdx.x * 32;
    const int mg   = m0 + wc * 16 + (lane & 15);

    // ---- preload Wp slice: 6144 16B-slots; physical slot p holds logical slot (p%48)^(row&7)
    // lds row r -> Wp row (r>>5)*256 + m0 + (r&31)
    #pragma unroll
    for (int i = 0; i < 24; ++i){
        int p0 = wid * 1536 + i * 64;          // wave-uniform dest base slot
        int p  = p0 + lane;                    // this lane's physical slot
        int lrow  = p / 48;
        int pslot = p % 48;
        int lslot = pslot ^ (lrow & 7);
        int grow  = (lrow >> 5) * 256 + m0 + (lrow & 31);
        gld_lds16(Wp + (size_t)grow * KTOT + lslot * 8, (char*)WpL + (size_t)p0 * 16);
    }

    const float b0 = bp[0 * 256 + mg];
    const float b1 = bp[1 * 256 + mg];
    const float b2 = bp[2 * 256 + mg];
    const float b3 = bp[3 * 256 + mg];

    asm volatile("s_waitcnt vmcnt(0)" ::: "memory");
    __builtin_amdgcn_s_barrier();

    unsigned gen = 0;
    for (int l = TAIL_TOP; l >= 0; --l){
        const int n = 1 << l;
        const unsigned short* Al = arena + offA(l);

        // ---- batched stage: A panel rows [0,n) x 384 -> AL (slot-XOR pre-swizzled source)
        const int nslots = n * 48;                 // 16B slots
        for (int t = 0; t * 256 < nslots; ++t){
            int pbase = t * 256 + wid * 64;        // wave-uniform dest base slot
            int p = pbase + lane;
            if (p < nslots){
                int row   = p / 48;
                int pslot = p - row * 48;
                int lslot = pslot ^ (row & 7);
                gld_lds16(Al + (size_t)row * KTOT + lslot * 8, (char*)AL + (size_t)pbase * 16);
            }
        }

        // ---- concurrent csum prefetch (latency overlaps the stage)
        float cpre[2][4];
        #pragma unroll
        for (int r = 0; r < 2; ++r){
            const int base = wm * 32 + r * 16 + (lane >> 4) * 4;
            #pragma unroll
            for (int e = 0; e < 4; ++e)
                cpre[r][e] = cs_in[(size_t)(base + e) * MEM + mg];   // always in-allocation
        }

        asm volatile("s_waitcnt vmcnt(0)" ::: "memory");
        __builtin_amdgcn_s_barrier();

        f32x4 acc[2][4];
        #pragma unroll
        for (int r = 0; r < 2; ++r)
            #pragma unroll
            for (int q = 0; q < 4; ++q)
                acc[r][q] = (f32x4){0.f, 0.f, 0.f, 0.f};

        #pragma unroll
        for (int kc = 0; kc < 12; ++kc){
            const int ls = kc * 4 + (lane >> 4);               // logical 16B slot
            const int kb = (ls ^ (lane & 7)) * 8;              // swizzled slot (row&7 == lane&7)
            s16x8 a[2], b[4];
            #pragma unroll
            for (int r = 0; r < 2; ++r)
                a[r] = *(const s16x8*)(AL + (size_t)(wm * 32 + r * 16 + (lane & 15)) * KTOT + kb);
            #pragma unroll
            for (int q = 0; q < 4; ++q)
                b[q] = *(const s16x8*)(WpL + (q * 32 + wc * 16 + (lane & 15)) * KTOT + kb);
            #pragma unroll
            for (int r = 0; r < 2; ++r)
                #pragma unroll
                for (int q = 0; q < 4; ++q)
                    acc[r][q] = __builtin_amdgcn_mfma_f32_16x16x32_bf16(a[r], b[q], acc[r][q], 0, 0, 0);
        }

        #pragma unroll
        for (int r = 0; r < 2; ++r){
            const int base = wm * 32 + r * 16 + (lane >> 4) * 4;
            float cn[4], hn[4];
            #pragma unroll
            for (int e = 0; e < 4; ++e){
                float iv = acc[r][0][e] + b0;
                float fv = acc[r][1][e] + b1;
                float gv = acc[r][2][e] + b2;
                float ov = acc[r][3][e] + b3;
                float c  = fsigm(fv) * cpre[r][e] + fsigm(iv) * ftanh(gv);
                cn[e] = c;
                hn[e] = fsigm(ov) * ftanh(c);
            }
            if (l == 0){
                if (base == 0) c_root[mg] = cn[0];
            } else {
                unsigned short* A_next = (unsigned short*)arena + offA(l - 1);
                if (base < n){
                    int p0 = base >> 1;
                    A_next[(size_t)p0 * KTOT + IN_DIM + mg] = f2bf(hn[0] + hn[1]);
                    cs_out[(size_t)p0 * MEM + mg] = cn[0] + cn[1];
                }
                if (base + 2 < n){
                    int p1 = (base >> 1) + 1;
                    A_next[(size_t)p1 * KTOT + IN_DIM + mg] = f2bf(hn[2] + hn[3]);
                    cs_out[(size_t)p1 * MEM + mg] = cn[2] + cn[3];
                }
            }
        }
        float* t = cs_in; cs_in = cs_out; cs_out = t;   // lockstep swap
        ++gen;
        grid_barrier(ctr, (unsigned)(NBLK_TAIL * gen));
    }

    // -------- FC on block 0: out[cls] = c_root . W_fc[cls] + b_fc[cls]
    if (blockIdx.x == 0){
        int w = wid;                   // 0..3
        for (int cls = w * 3; cls < w * 3 + 3; ++cls){
            float s = 0.f;
            for (int m = lane; m < 256; m += 64)
                s += c_root[m] * W_fc[cls * 256 + m];
            #pragma unroll
            for (int off = 32; off; off >>= 1)
                s += __shfl_down(s, off, 64);
            if (lane == 0) out[cls] = s + b_fc[cls];
        }
    }
}

extern "C" void kernel_launch(void* const* d_in, const int* in_sizes, int n_in,
                              void* d_out, int out_size, void* d_ws, size_t ws_size,
                              hipStream_t stream)
{
    const float* x    = (const float*)d_in[0];
    const float* W_ih = (const float*)d_in[1];
    const float* b_ih = (const float*)d_in[2];
    const float* W_hh = (const float*)d_in[3];
    const float* b_hh = (const float*)d_in[4];
    const float* W_fc = (const float*)d_in[5];
    const float* b_fc = (const float*)d_in[6];
    float* out = (float*)d_out;

    // workspace layout (bytes)
    const size_t OFF_WP = 0;                                   // 786432
    const size_t OFF_BP = 786432;                              // 4096
    const size_t OFF_A  = 790528;                              // (33554048+65536)*2
    const size_t OFF_CS0 = OFF_A + (size_t)(ARENA_ELEMS + ARENA_PAD) * 2;   // 33554432
    const size_t OFF_CS1 = OFF_CS0 + 33554432;                 // 33554432
    const size_t OFF_CR  = OFF_CS1 + 33554432;                 // 1024
    const size_t OFF_CTR = OFF_CR + 1024;                      // 64
    const size_t NEEDED  = OFF_CTR + 64;
    if (ws_size < NEEDED) return;

    char* ws = (char*)d_ws;
    unsigned short* Wp    = (unsigned short*)(ws + OFF_WP);
    float* bp             = (float*)(ws + OFF_BP);
    unsigned short* arena = (unsigned short*)(ws + OFF_A);
    float* cs0            = (float*)(ws + OFF_CS0);
    float* cs1            = (float*)(ws + OFF_CS1);
    float* c_root         = (float*)(ws + OFF_CR);
    unsigned* ctr         = (unsigned*)(ws + OFF_CTR);

    pack_w_kernel<<<dim3(1024), dim3(128), 0, stream>>>(W_ih, b_ih, W_hh, b_hh, Wp, bp, ctr);
    pack_x_kernel<<<dim3(2048), dim3(256), 0, stream>>>(x, arena);

    // ---- leaf level (l=16): n=65536, K=128; writes hsum into A(15), csum into cs0
    gemm_lstm_kernel<IN_DIM><<<dim3(NLEAF / BM, 8), dim3(256), 0, stream>>>(
        arena + offA(16), NLEAF, Wp, bp,
        nullptr, 1, arena + offA(15), cs0);

    float* cs_in = cs0; float* cs_out = cs1;
    for (int l = 15; l >= 7; --l){
        int n = 1 << l;
        gemm_lstm_kernel<KTOT><<<dim3(n / BM, 8), dim3(256), 0, stream>>>(
            arena + offA(l), n, Wp, bp,
            cs_in, 0, arena + offA(l - 1), cs_out);
        float* t = cs_in; cs_in = cs_out; cs_out = t;
    }

    // ---- tail: levels 6..0 + FC in one kernel (8 co-resident blocks + grid barrier)
    tail_kernel<<<dim3(NBLK_TAIL), dim3(256), 0, stream>>>(
        arena, Wp, bp, cs_in, cs_out, c_root, W_fc, b_fc, out, ctr);
}